// Round 7
// baseline (296.809 us; speedup 1.0000x reference)
//
#include <hip/hip_runtime.h>

// GraphNet interaction network. Edge MLP via bf16 MFMA (fp32 accum).
// V16: FUSED edge+obj+fc into ONE kernel (2 dispatches total).
// Evidence r0-r6: total == edge + ~121us in every round; generous per-kernel
// estimates leave ~100us of launch/drain overhead for the 4-dispatch chain.
// Fix: 256 blocks x 256 thr (<=1 block/CU; even at 256 VGPR 2 blocks/CU fit,
// so all blocks always resident -> deadlock-safe), hand-rolled device-scope
// generation barrier (__hip_atomic AGENT + threadfence; no cooperative-launch
// API inside graph capture). prep kernel zeroes the barrier slot.
// Edge phase: V13 structure (zero LDS, peeled s=0/s2=0 bias C-init, mask on
// tile 11 only, cvt_pk, E1 prefetch), 6 receivers/wave (prologue amortized
// 6x). V15's AGPR pinning REVERTED (spilled: WRITE 141KB->27.8MB, +12us).
// Obj phase: RT=16, grid-stride 376 chunks, 256 thr. Fc phase: blocks 0..31.
#define BB   32
#define NN   188
#define PP   16
#define HID  128
#define HH2  64
#define DE   5
#define DO   6
#define NT   5
#define ROWS_O (BB*NN)
#define RTO  16
#define KO   (PP+DE)
#define NBLK 256

typedef __attribute__((ext_vector_type(8))) short short8;     // 8 bf16 = 4 VGPRs
typedef __attribute__((ext_vector_type(4))) float float4_;
typedef __attribute__((ext_vector_type(4))) unsigned uint4_;

__device__ __forceinline__ short f2bf(float v) {              // RNE (prep only)
    union { float f; unsigned u; } a; a.f = v;
    unsigned r = a.u + 0x7fff + ((a.u >> 16) & 1);
    return (short)(r >> 16);
}
// relu both, then pack to 2xbf16 (RNE)
__device__ __forceinline__ unsigned relu_pk(float lo, float hi) {
    float l = lo > 0.f ? lo : 0.f;
    float h = hi > 0.f ? hi : 0.f;
    unsigned r;
    asm("v_cvt_pk_bf16_f32 %0, %1, %2" : "=v"(r) : "v"(l), "v"(h));
    return r;
}
__device__ __forceinline__ float4_ mfma16(short8 a, short8 b, float4_ c) {
    return __builtin_amdgcn_mfma_f32_16x16x32_bf16(a, b, c, 0, 0, 0);
}

// workspace layout (shorts)
#define XB_OFF    0                        // bf16 [32][188][24]
#define XB_ELTS   (BB*NN*24)               // 144384
#define W1S_OFF   (XB_OFF + XB_ELTS)       // A-frags [8 f][64 lanes][8]
#define W1S_ELTS  (8*64*8)                 // 4096
#define W2S_OFF   (W1S_OFF + W1S_ELTS)     // A-frags [16 f][64 lanes][8]
#define W2S_ELTS  (16*64*8)                // 8192
#define W3S_OFF   (W2S_OFF + W2S_ELTS)     // A-frags [2 s][64 lanes][8]
#define W3S_ELTS  (2*64*8)                 // 1024
#define SHORT_TOTAL (W3S_OFF + W3S_ELTS)

// MFMA-k position (q, e) -> neuron offset within a 32-block
__device__ __forceinline__ int kmap(int q, int e) {
    return (e < 4) ? (q*4 + e) : (16 + q*4 + (e - 4));
}

// device-scope generation barrier. bar[0]=arrive count, bar[1]=generation.
// Safe for repeated use; prep zeroes bar each launch (workspace is poisoned).
__device__ __forceinline__ void grid_sync(int* bar) {
    __threadfence();                      // release this block's global writes
    __syncthreads();
    if (threadIdx.x == 0) {
        int gen = __hip_atomic_load(bar + 1, __ATOMIC_RELAXED, __HIP_MEMORY_SCOPE_AGENT);
        int prev = __hip_atomic_fetch_add(bar, 1, __ATOMIC_ACQ_REL, __HIP_MEMORY_SCOPE_AGENT);
        if (prev == (int)gridDim.x - 1) {
            __hip_atomic_store(bar, 0, __ATOMIC_RELAXED, __HIP_MEMORY_SCOPE_AGENT);
            __hip_atomic_fetch_add(bar + 1, 1, __ATOMIC_RELEASE, __HIP_MEMORY_SCOPE_AGENT);
        } else {
            while (__hip_atomic_load(bar + 1, __ATOMIC_ACQUIRE, __HIP_MEMORY_SCOPE_AGENT) == gen)
                __builtin_amdgcn_s_sleep(2);
        }
    }
    __syncthreads();
    __threadfence();                      // acquire: invalidate before reading
}

__global__ void prep_kernel(const float* __restrict__ x,
                            const float* __restrict__ w1,
                            const float* __restrict__ w2,
                            const float* __restrict__ w3,
                            short* __restrict__ ws,
                            int* __restrict__ bar)
{
    const int i = blockIdx.x * blockDim.x + threadIdx.x;
    const int stride = gridDim.x * blockDim.x;
    if (i == 0) { bar[0] = 0; bar[1] = 0; }                  // barrier reset
    for (int idx = i; idx < BB*NN*PP; idx += stride) {       // x -> xb
        int row = idx >> 4, k = idx & 15;
        ws[XB_OFF + row*24 + k] = f2bf(x[idx]);
    }
    for (int idx = i; idx < W1S_ELTS; idx += stride) {       // w1 -> A-frags
        int t = idx >> 9;
        int l = (idx >> 3) & 63;
        int e = idx & 7;
        int q = l >> 4, n16 = l & 15;
        ws[W1S_OFF + idx] = f2bf(w1[(q*8 + e)*HID + t*16 + n16]);
    }
    for (int idx = i; idx < W2S_ELTS; idx += stride) {       // w2 -> A-frags
        int f = idx >> 9;
        int l = (idx >> 3) & 63;
        int e = idx & 7;
        int tt = f >> 2, s = f & 3;
        int q = l >> 4, n16 = l & 15;
        int k = 32*s + kmap(q, e);
        int n = tt*16 + n16;
        ws[W2S_OFF + idx] = f2bf(w2[k*HH2 + n]);
    }
    for (int idx = i; idx < W3S_ELTS; idx += stride) {       // w3 -> A-frags
        int s2 = idx >> 9;
        int l = (idx >> 3) & 63;
        int e = idx & 7;
        int q = l >> 4, n16 = l & 15;
        int k = 32*s2 + kmap(q, e);
        ws[W3S_OFF + idx] = (n16 < DE) ? f2bf(w3[k*DE + n16]) : (short)0;
    }
}

// One edge-tile (V13): layer1(2 MFMA + pack) x4 s-steps fused with layer2,
// then layer3. s=0 / s2=0 peeled: bias enters as MFMA C-in.
#define EDGE_TILE(E1C, MASKED, TI)                                              \
    {                                                                           \
        float4_ C2[4];                                                          \
        {                                                                       \
            float4_ Ca = mfma16(W1f[0], (E1C), cbv[0]);                         \
            float4_ Cb = mfma16(W1f[1], (E1C), cbv[1]);                         \
            uint4_ dv = (uint4_){ relu_pk(Ca[0], Ca[1]), relu_pk(Ca[2], Ca[3]),  \
                                  relu_pk(Cb[0], Cb[1]), relu_pk(Cb[2], Cb[3]) };\
            short8 Bf = __builtin_bit_cast(short8, dv);                         \
            C2[0] = mfma16(W2f[0],  Bf, bias2v[0]);                             \
            C2[1] = mfma16(W2f[4],  Bf, bias2v[1]);                             \
            C2[2] = mfma16(W2f[8],  Bf, bias2v[2]);                             \
            C2[3] = mfma16(W2f[12], Bf, bias2v[3]);                             \
        }                                                                       \
        _Pragma("unroll")                                                       \
        for (int s = 1; s < 4; ++s) {                                           \
            float4_ Ca = mfma16(W1f[2*s],   (E1C), cbv[2*s]);                   \
            float4_ Cb = mfma16(W1f[2*s+1], (E1C), cbv[2*s+1]);                 \
            uint4_ dv = (uint4_){ relu_pk(Ca[0], Ca[1]), relu_pk(Ca[2], Ca[3]),  \
                                  relu_pk(Cb[0], Cb[1]), relu_pk(Cb[2], Cb[3]) };\
            short8 Bf = __builtin_bit_cast(short8, dv);                         \
            C2[0] = mfma16(W2f[s],    Bf, C2[0]);                               \
            C2[1] = mfma16(W2f[4+s],  Bf, C2[1]);                               \
            C2[2] = mfma16(W2f[8+s],  Bf, C2[2]);                               \
            C2[3] = mfma16(W2f[12+s], Bf, C2[3]);                               \
        }                                                                       \
        float4_ C3;                                                             \
        {                                                                       \
            uint4_ dv = (uint4_){ relu_pk(C2[0][0], C2[0][1]), relu_pk(C2[0][2], C2[0][3]), \
                                  relu_pk(C2[1][0], C2[1][1]), relu_pk(C2[1][2], C2[1][3]) }; \
            C3 = mfma16(W3f[0], __builtin_bit_cast(short8, dv), bias3r);        \
        }                                                                       \
        {                                                                       \
            uint4_ dv = (uint4_){ relu_pk(C2[2][0], C2[2][1]), relu_pk(C2[2][2], C2[2][3]), \
                                  relu_pk(C2[3][0], C2[3][1]), relu_pk(C2[3][2], C2[3][3]) }; \
            C3 = mfma16(W3f[1], __builtin_bit_cast(short8, dv), C3);            \
        }                                                                       \
        if (MASKED) {                                                           \
            const bool ok = ((TI)*16 + n16 < NN-1);                             \
            _Pragma("unroll")                                                   \
            for (int rg = 0; rg < 4; ++rg) {                                    \
                float v = C3[rg] > 0.f ? C3[rg] : 0.f;                          \
                acc[rg] += ok ? v : 0.f;                                        \
            }                                                                   \
        } else {                                                                \
            _Pragma("unroll")                                                   \
            for (int rg = 0; rg < 4; ++rg)                                      \
                acc[rg] += C3[rg] > 0.f ? C3[rg] : 0.f;                         \
        }                                                                       \
    }

// ---------------------------------------------------------------------------
// FUSED kernel: phase E (edge MLP) -> grid_sync -> phase O (object MLP) ->
// grid_sync -> phase F (classifier). 256 blocks x 256 threads.
// ---------------------------------------------------------------------------
__global__ __launch_bounds__(256)
void fused_kernel(const short* __restrict__ ws_s,
                  const float* __restrict__ fr1_b,
                  const float* __restrict__ fr2_b,
                  const float* __restrict__ fr3_b,
                  float* __restrict__ ebar,
                  const float* __restrict__ x,
                  const float* __restrict__ fo1_w, const float* __restrict__ fo1_b,
                  const float* __restrict__ fo2_w, const float* __restrict__ fo2_b,
                  const float* __restrict__ fo3_w, const float* __restrict__ fo3_b,
                  float* __restrict__ o_ws,
                  const float* __restrict__ fc1_w, const float* __restrict__ fc1_b,
                  const float* __restrict__ fc2_w, const float* __restrict__ fc2_b,
                  const float* __restrict__ fc3_w, const float* __restrict__ fc3_b,
                  float* __restrict__ out,
                  int* __restrict__ bar)
{
    // ---- shared memory (obj + fc phases; edge phase uses none) ----
    __shared__ float sW[HID*HH2];          // 32 KB
    __shared__ float sB1[HID];
    __shared__ float sB2[HH2];
    __shared__ float sCin[RTO*KO];
    __shared__ float sH1[RTO*HID];
    __shared__ float sH2t[HH2*(RTO+1)];
    __shared__ __align__(16) float s_in[NN*DO];
    __shared__ float s_p[256];
    __shared__ float s_h1[HID];
    __shared__ float s_h2[HH2];

    const int tid  = threadIdx.x;
    const int wave = tid >> 6;
    const int lane = tid & 63;
    const int n16  = lane & 15;
    const int q    = lane >> 4;

    // ======================= PHASE E: edge MLP =======================
    {
        const short* xb  = ws_s + XB_OFF;
        const short* w1g = ws_s + W1S_OFF;
        const short* w2g = ws_s + W2S_OFF;
        const short* w3g = ws_s + W3S_OFF;

        short8 W1f[8];
        #pragma unroll
        for (int t = 0; t < 8; ++t)
            W1f[t] = *(const short8*)(w1g + t*512 + lane*8);
        short8 W2f[16];
        #pragma unroll
        for (int f = 0; f < 16; ++f)
            W2f[f] = *(const short8*)(w2g + f*512 + lane*8);
        short8 W3f[2];
        #pragma unroll
        for (int s = 0; s < 2; ++s)
            W3f[s] = *(const short8*)(w3g + s*512 + lane*8);
        float4_ cbv[8];
        #pragma unroll
        for (int t = 0; t < 8; ++t)
            cbv[t] = *(const float4_*)(fr1_b + t*16 + q*4);
        float4_ bias2v[4];
        #pragma unroll
        for (int tt = 0; tt < 4; ++tt)
            bias2v[tt] = *(const float4_*)(fr2_b + tt*16 + q*4);
        float4_ bias3r;
        #pragma unroll
        for (int rg = 0; rg < 4; ++rg) {
            int o = q*4 + rg;
            bias3r[rg] = (o < DE) ? fr3_b[o] : 0.f;
        }
        const bool rside = (q < 2);
        const int qoff = (q & 1)*8;
        const int gwave = blockIdx.x*4 + wave;      // 0..1023

        #pragma unroll 1
        for (int j = 0; j < 6; ++j) {
            const int bi = gwave + j*1024;          // wave-uniform
            if (bi < ROWS_O) {
                const int b    = bi / NN;
                const int recv = bi - b*NN;
                const short* xrow = xb + b*(NN*24);
                float acc[4] = {0.f, 0.f, 0.f, 0.f};

                short8 E1;
                {
                    int send0 = n16 + (n16 >= recv ? 1 : 0);
                    const int node = rside ? recv : send0;
                    E1 = *(const short8*)(xrow + node*24 + qoff);
                }
                #pragma unroll 1
                for (int ti = 0; ti < 11; ++ti) {
                    short8 E1c = E1;
                    {
                        int en = (ti+1)*16 + n16;
                        int send = en + (en >= recv ? 1 : 0);
                        if (send > NN-1) send = NN-1;
                        const int node = rside ? recv : send;
                        E1 = *(const short8*)(xrow + node*24 + qoff);
                    }
                    EDGE_TILE(E1c, false, ti)
                }
                EDGE_TILE(E1, true, 11)

                #pragma unroll
                for (int rg = 0; rg < 4; ++rg) {
                    acc[rg] += __shfl_xor(acc[rg], 1);
                    acc[rg] += __shfl_xor(acc[rg], 2);
                    acc[rg] += __shfl_xor(acc[rg], 4);
                    acc[rg] += __shfl_xor(acc[rg], 8);
                }
                if (n16 == 0) {
                    #pragma unroll
                    for (int rg = 0; rg < 4; ++rg) {
                        int o = q*4 + rg;
                        if (o < DE) ebar[bi*DE + o] = acc[rg];
                    }
                }
            }
        }
    }

    grid_sync(bar);

    // ======================= PHASE O: object MLP =======================
    #pragma unroll 1
    for (int chunk = blockIdx.x; chunk < ROWS_O/RTO; chunk += gridDim.x) {
        const int rbase = chunk * RTO;

        for (int i = tid; i < KO*HID; i += 256) sW[i] = fo1_w[i];
        if (tid < HID) sB1[tid] = fo1_b[tid];
        else if (tid < HID+HH2) sB2[tid-HID] = fo2_b[tid-HID];
        for (int i = tid; i < RTO*KO; i += 256) {
            int r = i / KO, k = i - r*KO;
            int gr = rbase + r;
            int b = gr / NN;
            int node = gr - b*NN;
            sCin[i] = (k < PP) ? x[(b*NN+node)*PP + k]
                               : ebar[(b*NN+node)*DE + (k-PP)];
        }
        __syncthreads();

        {   // layer 1: 2 groups x 8 rows
            const int j = tid & (HID-1);
            const int g = tid >> 7;
            float w[KO];
            #pragma unroll
            for (int k = 0; k < KO; ++k) w[k] = sW[k*HID + j];
            const float bj = sB1[j];
            #pragma unroll
            for (int rr = 0; rr < 8; ++rr) {
                const int r = g*8 + rr;
                const float* e = &sCin[r*KO];
                float a0=0.f,a1=0.f,a2=0.f;
                #pragma unroll
                for (int k = 0; k < KO; k += 3) {
                    a0 += w[k+0]*e[k+0];
                    a1 += w[k+1]*e[k+1];
                    a2 += w[k+2]*e[k+2];
                }
                float v = a0+a1+a2+bj;
                sH1[r*HID + j] = v > 0.f ? v : 0.f;
            }
        }
        __syncthreads();
        for (int i = tid; i < HID*HH2; i += 256) sW[i] = fo2_w[i];
        __syncthreads();

        {   // layer 2: 4 groups x 4 rows
            const int j = tid & (HH2-1);
            const int g = tid >> 6;
            float acc2[4];
            #pragma unroll
            for (int rr = 0; rr < 4; ++rr) acc2[rr] = sB2[j];
            #pragma unroll
            for (int kc = 0; kc < HID; kc += 32) {
                float w[32];
                #pragma unroll
                for (int kk = 0; kk < 32; ++kk) w[kk] = sW[(kc+kk)*HH2 + j];
                #pragma unroll
                for (int rr = 0; rr < 4; ++rr) {
                    const float* h = &sH1[(g*4+rr)*HID + kc];
                    float a0=0.f,a1=0.f,a2=0.f,a3=0.f;
                    #pragma unroll
                    for (int kk = 0; kk < 32; kk += 4) {
                        a0 += w[kk+0]*h[kk+0];
                        a1 += w[kk+1]*h[kk+1];
                        a2 += w[kk+2]*h[kk+2];
                        a3 += w[kk+3]*h[kk+3];
                    }
                    acc2[rr] += (a0+a1)+(a2+a3);
                }
            }
            #pragma unroll
            for (int rr = 0; rr < 4; ++rr) {
                float v = acc2[rr];
                sH2t[j*(RTO+1) + (g*4+rr)] = v > 0.f ? v : 0.f;
            }
        }
        __syncthreads();

        if (tid < RTO*DO) {     // layer 3
            const int r = tid & (RTO-1);
            const int c = tid >> 4;
            float a0=0.f,a1=0.f,a2=0.f,a3=0.f;
            #pragma unroll
            for (int k = 0; k < HH2; k += 4) {
                a0 += sH2t[(k+0)*(RTO+1)+r]*fo3_w[(k+0)*DO+c];
                a1 += sH2t[(k+1)*(RTO+1)+r]*fo3_w[(k+1)*DO+c];
                a2 += sH2t[(k+2)*(RTO+1)+r]*fo3_w[(k+2)*DO+c];
                a3 += sH2t[(k+3)*(RTO+1)+r]*fo3_w[(k+3)*DO+c];
            }
            float v = (a0+a1)+(a2+a3) + fo3_b[c];
            v = v > 0.f ? v : 0.f;
            int gr = rbase + r;
            int b = gr / NN;
            int node = gr - b*NN;
            o_ws[b*(NN*DO) + node*DO + c] = v;
        }
        __syncthreads();        // before next chunk overwrites sW/sCin
    }

    grid_sync(bar);

    // ======================= PHASE F: classifier =======================
    if (blockIdx.x < BB) {
        const int b = blockIdx.x;

        for (int i = tid; i < NN*DO; i += 256) s_in[i] = o_ws[b*(NN*DO) + i];
        __syncthreads();

        {
            const int j = tid & (HID-1);
            const int h = tid >> 7;
            const float4* s4 = (const float4*)&s_in[h*564];
            const float* wbase = fc1_w + (size_t)(h*564)*HID + j;
            float a0=0.f,a1=0.f,a2=0.f,a3=0.f;
            #pragma unroll 4
            for (int i = 0; i < 141; ++i) {
                float4 v = s4[i];
                const float* wp = wbase + (size_t)i*4*HID;
                a0 += v.x * wp[0];
                a1 += v.y * wp[HID];
                a2 += v.z * wp[2*HID];
                a3 += v.w * wp[3*HID];
            }
            s_p[tid] = (a0+a1)+(a2+a3);
        }
        __syncthreads();
        if (tid < HID) {
            float v = s_p[tid] + s_p[tid+HID] + fc1_b[tid];
            s_h1[tid] = v > 0.f ? v : 0.f;
        }
        __syncthreads();

        {
            const int j = tid & (HH2-1);
            const int qq = tid >> 6;
            float acc3 = 0.f;
            #pragma unroll
            for (int kk = 0; kk < 32; ++kk) {
                int k = qq*32 + kk;
                acc3 += s_h1[k] * fc2_w[k*HH2 + j];
            }
            s_p[tid] = acc3;
        }
        __syncthreads();
        if (tid < HH2) {
            float v = s_p[tid] + s_p[tid+64] + s_p[tid+128] + s_p[tid+192] + fc2_b[tid];
            s_h2[tid] = v > 0.f ? v : 0.f;
        }
        __syncthreads();

        if (tid < NT) {
            float acc3 = fc3_b[tid];
            #pragma unroll
            for (int k = 0; k < HH2; ++k)
                acc3 += s_h2[k] * fc3_w[k*NT + tid];
            out[b*NT + tid] = acc3;
        }
    }
}

extern "C" void kernel_launch(void* const* d_in, const int* in_sizes, int n_in,
                              void* d_out, int out_size, void* d_ws, size_t ws_size,
                              hipStream_t stream) {
    (void)in_sizes; (void)n_in; (void)out_size; (void)ws_size;
    const float* x     = (const float*)d_in[0];
    const float* fr1_w = (const float*)d_in[1];
    const float* fr1_b = (const float*)d_in[2];
    const float* fr2_w = (const float*)d_in[3];
    const float* fr2_b = (const float*)d_in[4];
    const float* fr3_w = (const float*)d_in[5];
    const float* fr3_b = (const float*)d_in[6];
    const float* fo1_w = (const float*)d_in[7];
    const float* fo1_b = (const float*)d_in[8];
    const float* fo2_w = (const float*)d_in[9];
    const float* fo2_b = (const float*)d_in[10];
    const float* fo3_w = (const float*)d_in[11];
    const float* fo3_b = (const float*)d_in[12];
    const float* fc1_w = (const float*)d_in[13];
    const float* fc1_b = (const float*)d_in[14];
    const float* fc2_w = (const float*)d_in[15];
    const float* fc2_b = (const float*)d_in[16];
    const float* fc3_w = (const float*)d_in[17];
    const float* fc3_b = (const float*)d_in[18];

    short* ws_s = (short*)d_ws;
    size_t fbase = ((size_t)SHORT_TOTAL*2 + 15) & ~(size_t)15;
    float* ebar = (float*)((char*)d_ws + fbase);            // [32][188][5]
    float* o_ws = ebar + BB*NN*DE;                          // [32][188][6]
    int*   bar  = (int*)(o_ws + BB*NN*DO);                  // [2]

    prep_kernel<<<128, 256, 0, stream>>>(x, fr1_w, fr2_w, fr3_w, ws_s, bar);
    fused_kernel<<<NBLK, 256, 0, stream>>>(
        ws_s, fr1_b, fr2_b, fr3_b, ebar,
        x, fo1_w, fo1_b, fo2_w, fo2_b, fo3_w, fo3_b, o_ws,
        fc1_w, fc1_b, fc2_w, fc2_b, fc3_w, fc3_b, (float*)d_out, bar);
}

// Round 8
// 147.567 us; speedup vs baseline: 2.0113x; 2.0113x over previous
//
#include <hip/hip_runtime.h>

// GraphNet interaction network. Edge MLP via bf16 MFMA (fp32 accum).
// V17: DE-STRAGGLE obj/fc. r5-r7 inference: all non-edge kernels are <40us
// individually (below the 40us fill dispatches in r5's top-5) yet sum to
// ~121us -> obj (188 blocks, 0.73/CU) and fc (32 blocks, 1/8 of chip) are
// low-parallelism L2-latency stragglers. Fixes: obj RT 32->16 at 376 blocks;
// fc split into fc1 (1128x128 GEMV, 256 blocks: one per (b,16-col group),
// 16-way k-split + LDS reduce) and fc23 (32 blocks, trivial). Edge kernel is
// V13 VERBATIM (measured 39.9us): zero LDS, reg-resident frags, peeled
// s=0/s2=0 bias C-init, mask on tile 11 only, cvt_pk packs, E1 prefetch.
// V16's fusion REVERTED (218us: 1 block/CU killed TLP).
#define BB   32
#define NN   188
#define PP   16
#define HID  128
#define HH2  64
#define DE   5
#define DO   6
#define NT   5
#define ROWS_O (BB*NN)
#define RTO  16
#define KO   (PP+DE)

typedef __attribute__((ext_vector_type(8))) short short8;     // 8 bf16 = 4 VGPRs
typedef __attribute__((ext_vector_type(4))) float float4_;
typedef __attribute__((ext_vector_type(4))) unsigned uint4_;

__device__ __forceinline__ short f2bf(float v) {              // RNE (prep only)
    union { float f; unsigned u; } a; a.f = v;
    unsigned r = a.u + 0x7fff + ((a.u >> 16) & 1);
    return (short)(r >> 16);
}
// relu both, then pack to 2xbf16 (RNE)
__device__ __forceinline__ unsigned relu_pk(float lo, float hi) {
    float l = lo > 0.f ? lo : 0.f;
    float h = hi > 0.f ? hi : 0.f;
    unsigned r;
    asm("v_cvt_pk_bf16_f32 %0, %1, %2" : "=v"(r) : "v"(l), "v"(h));
    return r;
}
__device__ __forceinline__ float4_ mfma16(short8 a, short8 b, float4_ c) {
    return __builtin_amdgcn_mfma_f32_16x16x32_bf16(a, b, c, 0, 0, 0);
}

// workspace layout (shorts)
#define XB_OFF    0                        // bf16 [32][188][24]
#define XB_ELTS   (BB*NN*24)               // 144384
#define W1S_OFF   (XB_OFF + XB_ELTS)       // A-frags [8 f][64 lanes][8]
#define W1S_ELTS  (8*64*8)                 // 4096
#define W2S_OFF   (W1S_OFF + W1S_ELTS)     // A-frags [16 f][64 lanes][8]
#define W2S_ELTS  (16*64*8)                // 8192
#define W3S_OFF   (W2S_OFF + W2S_ELTS)     // A-frags [2 s][64 lanes][8]
#define W3S_ELTS  (2*64*8)                 // 1024
#define SHORT_TOTAL (W3S_OFF + W3S_ELTS)

// MFMA-k position (q, e) -> neuron offset within a 32-block
__device__ __forceinline__ int kmap(int q, int e) {
    return (e < 4) ? (q*4 + e) : (16 + q*4 + (e - 4));
}

__global__ void prep_kernel(const float* __restrict__ x,
                            const float* __restrict__ w1,
                            const float* __restrict__ w2,
                            const float* __restrict__ w3,
                            short* __restrict__ ws)
{
    const int i = blockIdx.x * blockDim.x + threadIdx.x;
    const int stride = gridDim.x * blockDim.x;
    for (int idx = i; idx < BB*NN*PP; idx += stride) {       // x -> xb
        int row = idx >> 4, k = idx & 15;
        ws[XB_OFF + row*24 + k] = f2bf(x[idx]);
    }
    for (int idx = i; idx < W1S_ELTS; idx += stride) {       // w1 -> A-frags
        int t = idx >> 9;
        int l = (idx >> 3) & 63;
        int e = idx & 7;
        int q = l >> 4, n16 = l & 15;
        ws[W1S_OFF + idx] = f2bf(w1[(q*8 + e)*HID + t*16 + n16]);
    }
    for (int idx = i; idx < W2S_ELTS; idx += stride) {       // w2 -> A-frags
        int f = idx >> 9;
        int l = (idx >> 3) & 63;
        int e = idx & 7;
        int tt = f >> 2, s = f & 3;
        int q = l >> 4, n16 = l & 15;
        int k = 32*s + kmap(q, e);
        int n = tt*16 + n16;
        ws[W2S_OFF + idx] = f2bf(w2[k*HH2 + n]);
    }
    for (int idx = i; idx < W3S_ELTS; idx += stride) {       // w3 -> A-frags
        int s2 = idx >> 9;
        int l = (idx >> 3) & 63;
        int e = idx & 7;
        int q = l >> 4, n16 = l & 15;
        int k = 32*s2 + kmap(q, e);
        ws[W3S_OFF + idx] = (n16 < DE) ? f2bf(w3[k*DE + n16]) : (short)0;
    }
}

// One edge-tile (V13): layer1(2 MFMA + pack) x4 s-steps fused with layer2,
// then layer3 (2 packs + 2 MFMA). s=0 / s2=0 peeled: bias enters as MFMA C-in.
#define EDGE_TILE(E1C, MASKED, TI)                                              \
    {                                                                           \
        float4_ C2[4];                                                          \
        {                                                                       \
            float4_ Ca = mfma16(W1f[0], (E1C), cbv[0]);                         \
            float4_ Cb = mfma16(W1f[1], (E1C), cbv[1]);                         \
            uint4_ dv = (uint4_){ relu_pk(Ca[0], Ca[1]), relu_pk(Ca[2], Ca[3]),  \
                                  relu_pk(Cb[0], Cb[1]), relu_pk(Cb[2], Cb[3]) };\
            short8 Bf = __builtin_bit_cast(short8, dv);                         \
            C2[0] = mfma16(W2f[0],  Bf, bias2v[0]);                             \
            C2[1] = mfma16(W2f[4],  Bf, bias2v[1]);                             \
            C2[2] = mfma16(W2f[8],  Bf, bias2v[2]);                             \
            C2[3] = mfma16(W2f[12], Bf, bias2v[3]);                             \
        }                                                                       \
        _Pragma("unroll")                                                       \
        for (int s = 1; s < 4; ++s) {                                           \
            float4_ Ca = mfma16(W1f[2*s],   (E1C), cbv[2*s]);                   \
            float4_ Cb = mfma16(W1f[2*s+1], (E1C), cbv[2*s+1]);                 \
            uint4_ dv = (uint4_){ relu_pk(Ca[0], Ca[1]), relu_pk(Ca[2], Ca[3]),  \
                                  relu_pk(Cb[0], Cb[1]), relu_pk(Cb[2], Cb[3]) };\
            short8 Bf = __builtin_bit_cast(short8, dv);                         \
            C2[0] = mfma16(W2f[s],    Bf, C2[0]);                               \
            C2[1] = mfma16(W2f[4+s],  Bf, C2[1]);                               \
            C2[2] = mfma16(W2f[8+s],  Bf, C2[2]);                               \
            C2[3] = mfma16(W2f[12+s], Bf, C2[3]);                               \
        }                                                                       \
        float4_ C3;                                                             \
        {                                                                       \
            uint4_ dv = (uint4_){ relu_pk(C2[0][0], C2[0][1]), relu_pk(C2[0][2], C2[0][3]), \
                                  relu_pk(C2[1][0], C2[1][1]), relu_pk(C2[1][2], C2[1][3]) }; \
            C3 = mfma16(W3f[0], __builtin_bit_cast(short8, dv), bias3r);        \
        }                                                                       \
        {                                                                       \
            uint4_ dv = (uint4_){ relu_pk(C2[2][0], C2[2][1]), relu_pk(C2[2][2], C2[2][3]), \
                                  relu_pk(C2[3][0], C2[3][1]), relu_pk(C2[3][2], C2[3][3]) }; \
            C3 = mfma16(W3f[1], __builtin_bit_cast(short8, dv), C3);            \
        }                                                                       \
        if (MASKED) {                                                           \
            const bool ok = ((TI)*16 + n16 < NN-1);                             \
            _Pragma("unroll")                                                   \
            for (int rg = 0; rg < 4; ++rg) {                                    \
                float v = C3[rg] > 0.f ? C3[rg] : 0.f;                          \
                acc[rg] += ok ? v : 0.f;                                        \
            }                                                                   \
        } else {                                                                \
            _Pragma("unroll")                                                   \
            for (int rg = 0; rg < 4; ++rg)                                      \
                acc[rg] += C3[rg] > 0.f ? C3[rg] : 0.f;                         \
        }                                                                       \
    }

// ---------------------------------------------------------------------------
// Edge MLP (V13 verbatim): 32 -> 128 relu -> 64 relu -> 5 relu, summed over
// 187 edges of one (batch, receiver). One receiver PER WAVE; 4 waves/block;
// ZERO LDS. 12 edge-tiles of 16 per wave, tile 11 peeled.
// ---------------------------------------------------------------------------
__global__ __launch_bounds__(256) __attribute__((amdgpu_waves_per_eu(2, 2)))
void edge_mfma_kernel(const short* __restrict__ ws_s,
                      const float* __restrict__ b1,
                      const float* __restrict__ b2,
                      const float* __restrict__ b3,
                      float* __restrict__ ebar)
{
    const short* xb  = ws_s + XB_OFF;
    const short* w1g = ws_s + W1S_OFF;
    const short* w2g = ws_s + W2S_OFF;
    const short* w3g = ws_s + W3S_OFF;

    const int tid  = threadIdx.x;
    const int wave = tid >> 6;
    const int lane = tid & 63;
    const int n16  = lane & 15;
    const int q    = lane >> 4;
    const int bi   = blockIdx.x * 4 + wave;   // b*188 + recv (one per wave)
    const int b    = bi / NN;
    const int recv = bi - b*NN;

    short8 W1f[8];
    #pragma unroll
    for (int t = 0; t < 8; ++t)
        W1f[t] = *(const short8*)(w1g + t*512 + lane*8);
    short8 W2f[16];
    #pragma unroll
    for (int f = 0; f < 16; ++f)
        W2f[f] = *(const short8*)(w2g + f*512 + lane*8);
    short8 W3f[2];
    #pragma unroll
    for (int s = 0; s < 2; ++s)
        W3f[s] = *(const short8*)(w3g + s*512 + lane*8);
    float4_ cbv[8];
    #pragma unroll
    for (int t = 0; t < 8; ++t)
        cbv[t] = *(const float4_*)(b1 + t*16 + q*4);
    float4_ bias2v[4];
    #pragma unroll
    for (int tt = 0; tt < 4; ++tt)
        bias2v[tt] = *(const float4_*)(b2 + tt*16 + q*4);
    float4_ bias3r;
    #pragma unroll
    for (int rg = 0; rg < 4; ++rg) {
        int o = q*4 + rg;
        bias3r[rg] = (o < DE) ? b3[o] : 0.f;
    }

    const short* xrow = xb + b*(NN*24);
    const bool rside = (q < 2);
    const int qoff = (q & 1)*8;

    float acc[4] = {0.f, 0.f, 0.f, 0.f};

    short8 E1;
    {
        int send0 = n16 + (n16 >= recv ? 1 : 0);
        const int node = rside ? recv : send0;
        E1 = *(const short8*)(xrow + node*24 + qoff);
    }

    #pragma unroll 1
    for (int ti = 0; ti < 11; ++ti) {
        short8 E1c = E1;
        {
            int en = (ti+1)*16 + n16;
            int send = en + (en >= recv ? 1 : 0);
            if (send > NN-1) send = NN-1;
            const int node = rside ? recv : send;
            E1 = *(const short8*)(xrow + node*24 + qoff);
        }
        EDGE_TILE(E1c, false, ti)
    }
    EDGE_TILE(E1, true, 11)

    #pragma unroll
    for (int rg = 0; rg < 4; ++rg) {
        acc[rg] += __shfl_xor(acc[rg], 1);
        acc[rg] += __shfl_xor(acc[rg], 2);
        acc[rg] += __shfl_xor(acc[rg], 4);
        acc[rg] += __shfl_xor(acc[rg], 8);
    }
    if (n16 == 0) {
        #pragma unroll
        for (int rg = 0; rg < 4; ++rg) {
            int o = q*4 + rg;
            if (o < DE) ebar[bi*DE + o] = acc[rg];
        }
    }
}

// ---------------------------------------------------------------------------
// Object MLP: [x(16)|Ebar(5)] -> 128 -> 64 -> 6 relu.
// RT=16 rows/block, 376 blocks x 256 threads (1.5 blocks/CU).
// ---------------------------------------------------------------------------
__global__ __launch_bounds__(256)
void obj_mlp_kernel(const float* __restrict__ x, const float* __restrict__ ebar,
                    const float* __restrict__ w1, const float* __restrict__ b1,
                    const float* __restrict__ w2, const float* __restrict__ b2,
                    const float* __restrict__ w3, const float* __restrict__ b3,
                    float* __restrict__ o_out)
{
    __shared__ float sW[HID*HH2];
    __shared__ float sB1[HID];
    __shared__ float sB2[HH2];
    __shared__ float sCin[RTO*KO];
    __shared__ float sH1[RTO*HID];
    __shared__ float sH2t[HH2*(RTO+1)];
    const int tid = threadIdx.x;
    const int rbase = blockIdx.x * RTO;

    for (int i = tid; i < KO*HID; i += 256) sW[i] = w1[i];
    if (tid < HID) sB1[tid] = b1[tid];
    else if (tid < HID+HH2) sB2[tid-HID] = b2[tid-HID];
    for (int i = tid; i < RTO*KO; i += 256) {
        int r = i / KO, k = i - r*KO;
        int gr = rbase + r;
        int b = gr / NN;
        int node = gr - b*NN;
        sCin[i] = (k < PP) ? x[(b*NN+node)*PP + k]
                           : ebar[(b*NN+node)*DE + (k-PP)];
    }
    __syncthreads();

    {   // layer 1: 2 groups x 8 rows
        const int j = tid & (HID-1);
        const int g = tid >> 7;
        float w[KO];
        #pragma unroll
        for (int k = 0; k < KO; ++k) w[k] = sW[k*HID + j];
        const float bj = sB1[j];
        #pragma unroll
        for (int rr = 0; rr < 8; ++rr) {
            const int r = g*8 + rr;
            const float* e = &sCin[r*KO];
            float a0=0.f,a1=0.f,a2=0.f;
            #pragma unroll
            for (int k = 0; k < KO; k += 3) {
                a0 += w[k+0]*e[k+0];
                a1 += w[k+1]*e[k+1];
                a2 += w[k+2]*e[k+2];
            }
            float v = a0+a1+a2+bj;
            sH1[r*HID + j] = v > 0.f ? v : 0.f;
        }
    }
    __syncthreads();
    for (int i = tid; i < HID*HH2; i += 256) sW[i] = w2[i];
    __syncthreads();

    {   // layer 2: 4 groups x 4 rows
        const int j = tid & (HH2-1);
        const int g = tid >> 6;
        float acc[4];
        #pragma unroll
        for (int rr = 0; rr < 4; ++rr) acc[rr] = sB2[j];
        #pragma unroll
        for (int kc = 0; kc < HID; kc += 32) {
            float w[32];
            #pragma unroll
            for (int kk = 0; kk < 32; ++kk) w[kk] = sW[(kc+kk)*HH2 + j];
            #pragma unroll
            for (int rr = 0; rr < 4; ++rr) {
                const float* h = &sH1[(g*4+rr)*HID + kc];
                float a0=0.f,a1=0.f,a2=0.f,a3=0.f;
                #pragma unroll
                for (int kk = 0; kk < 32; kk += 4) {
                    a0 += w[kk+0]*h[kk+0];
                    a1 += w[kk+1]*h[kk+1];
                    a2 += w[kk+2]*h[kk+2];
                    a3 += w[kk+3]*h[kk+3];
                }
                acc[rr] += (a0+a1)+(a2+a3);
            }
        }
        #pragma unroll
        for (int rr = 0; rr < 4; ++rr) {
            float v = acc[rr];
            sH2t[j*(RTO+1) + (g*4+rr)] = v > 0.f ? v : 0.f;
        }
    }
    __syncthreads();

    if (tid < RTO*DO) {     // layer 3
        const int r = tid & (RTO-1);
        const int c = tid >> 4;
        float a0=0.f,a1=0.f,a2=0.f,a3=0.f;
        #pragma unroll
        for (int k = 0; k < HH2; k += 4) {
            a0 += sH2t[(k+0)*(RTO+1)+r]*w3[(k+0)*DO+c];
            a1 += sH2t[(k+1)*(RTO+1)+r]*w3[(k+1)*DO+c];
            a2 += sH2t[(k+2)*(RTO+1)+r]*w3[(k+2)*DO+c];
            a3 += sH2t[(k+3)*(RTO+1)+r]*w3[(k+3)*DO+c];
        }
        float v = (a0+a1)+(a2+a3) + b3[c];
        v = v > 0.f ? v : 0.f;
        int gr = rbase + r;
        int b = gr / NN;
        int node = gr - b*NN;
        o_out[b*(NN*DO) + node*DO + c] = v;
    }
}

// ---------------------------------------------------------------------------
// Classifier layer 1: [32 b][1128] @ [1128][128] -> relu h1 [32][128].
// 256 blocks: one per (b, 16-col group). 16-way k-split per column + LDS
// reduce -> spreads the 577KB weight stream across the whole chip.
// ---------------------------------------------------------------------------
__global__ __launch_bounds__(256)
void fc1_kernel(const float* __restrict__ o_in,
                const float* __restrict__ w1, const float* __restrict__ b1,
                float* __restrict__ h1_ws)
{
    __shared__ __align__(16) float s_o[NN*DO];        // 1128 floats
    __shared__ float s_red[16][17];
    const int tid = threadIdx.x;
    const int b   = blockIdx.x >> 3;
    const int cg  = blockIdx.x & 7;

    for (int i = tid; i < NN*DO; i += 256) s_o[i] = o_in[b*(NN*DO) + i];
    __syncthreads();

    const int col = tid & 15;            // 0..15 within group
    const int sl  = tid >> 4;            // 0..15 k-slice
    const int jg  = cg*16 + col;         // global output column
    const int k0  = sl*71;
    const int k1  = (k0 + 71 < NN*DO) ? k0 + 71 : NN*DO;

    float a0=0.f, a1=0.f, a2=0.f, a3=0.f;
    int k = k0;
    for (; k + 3 < k1; k += 4) {
        a0 += s_o[k+0] * w1[(size_t)(k+0)*HID + jg];
        a1 += s_o[k+1] * w1[(size_t)(k+1)*HID + jg];
        a2 += s_o[k+2] * w1[(size_t)(k+2)*HID + jg];
        a3 += s_o[k+3] * w1[(size_t)(k+3)*HID + jg];
    }
    for (; k < k1; ++k)
        a0 += s_o[k] * w1[(size_t)k*HID + jg];
    s_red[col][sl] = (a0+a1)+(a2+a3);
    __syncthreads();

    if (tid < 16) {
        float t = 0.f;
        #pragma unroll
        for (int s = 0; s < 16; ++s) t += s_red[tid][s];
        t += b1[cg*16 + tid];
        h1_ws[b*HID + cg*16 + tid] = t > 0.f ? t : 0.f;
    }
}

// ---------------------------------------------------------------------------
// Classifier layers 2+3: h1[128] -> 64 relu -> 5. 32 blocks (one per b).
// ---------------------------------------------------------------------------
__global__ __launch_bounds__(256)
void fc23_kernel(const float* __restrict__ h1_ws,
                 const float* __restrict__ w2, const float* __restrict__ b2,
                 const float* __restrict__ w3, const float* __restrict__ b3,
                 float* __restrict__ out)
{
    __shared__ float s_h1[HID];
    __shared__ float s_p[256];
    __shared__ float s_h2[HH2];
    const int b = blockIdx.x, tid = threadIdx.x;

    if (tid < HID) s_h1[tid] = h1_ws[b*HID + tid];
    __syncthreads();

    {
        const int j = tid & (HH2-1);
        const int q = tid >> 6;
        float acc = 0.f;
        #pragma unroll
        for (int kk = 0; kk < 32; ++kk) {
            int k = q*32 + kk;
            acc += s_h1[k] * w2[k*HH2 + j];
        }
        s_p[tid] = acc;
    }
    __syncthreads();
    if (tid < HH2) {
        float v = s_p[tid] + s_p[tid+64] + s_p[tid+128] + s_p[tid+192] + b2[tid];
        s_h2[tid] = v > 0.f ? v : 0.f;
    }
    __syncthreads();

    if (tid < NT) {
        float acc = b3[tid];
        #pragma unroll
        for (int k = 0; k < HH2; ++k)
            acc += s_h2[k] * w3[k*NT + tid];
        out[b*NT + tid] = acc;
    }
}

extern "C" void kernel_launch(void* const* d_in, const int* in_sizes, int n_in,
                              void* d_out, int out_size, void* d_ws, size_t ws_size,
                              hipStream_t stream) {
    (void)in_sizes; (void)n_in; (void)out_size; (void)ws_size;
    const float* x     = (const float*)d_in[0];
    const float* fr1_w = (const float*)d_in[1];
    const float* fr1_b = (const float*)d_in[2];
    const float* fr2_w = (const float*)d_in[3];
    const float* fr2_b = (const float*)d_in[4];
    const float* fr3_w = (const float*)d_in[5];
    const float* fr3_b = (const float*)d_in[6];
    const float* fo1_w = (const float*)d_in[7];
    const float* fo1_b = (const float*)d_in[8];
    const float* fo2_w = (const float*)d_in[9];
    const float* fo2_b = (const float*)d_in[10];
    const float* fo3_w = (const float*)d_in[11];
    const float* fo3_b = (const float*)d_in[12];
    const float* fc1_w = (const float*)d_in[13];
    const float* fc1_b = (const float*)d_in[14];
    const float* fc2_w = (const float*)d_in[15];
    const float* fc2_b = (const float*)d_in[16];
    const float* fc3_w = (const float*)d_in[17];
    const float* fc3_b = (const float*)d_in[18];

    short* ws_s = (short*)d_ws;
    size_t fbase = ((size_t)SHORT_TOTAL*2 + 15) & ~(size_t)15;
    float* ebar  = (float*)((char*)d_ws + fbase);           // [32][188][5]
    float* o_ws  = ebar + BB*NN*DE;                         // [32][188][6]
    float* h1_ws = o_ws + BB*NN*DO;                         // [32][128]

    prep_kernel<<<128, 256, 0, stream>>>(x, fr1_w, fr2_w, fr3_w, ws_s);
    edge_mfma_kernel<<<(BB*NN)/4, 256, 0, stream>>>(ws_s, fr1_b, fr2_b, fr3_b, ebar);
    obj_mlp_kernel<<<ROWS_O/RTO, 256, 0, stream>>>(
        x, ebar, fo1_w, fo1_b, fo2_w, fo2_b, fo3_w, fo3_b, o_ws);
    fc1_kernel<<<BB*8, 256, 0, stream>>>(o_ws, fc1_w, fc1_b, h1_ws);
    fc23_kernel<<<BB, 256, 0, stream>>>(
        h1_ws, fc2_w, fc2_b, fc3_w, fc3_b, (float*)d_out);
}